// Round 1
// baseline (98.106 us; speedup 1.0000x reference)
//
#include <hip/hip_runtime.h>
#include <math.h>

#define NPTS 16384
#define NSMP_TOT 8192      // 8 * 1024
#define TILE 1024
#define KNN 10

__global__ __launch_bounds__(256) void softproj_kernel(
    const float* __restrict__ xyz,
    const float* __restrict__ sxyz,
    const float* __restrict__ temp,
    float* __restrict__ out)
{
    __shared__ float tileS[TILE * 3];
    const int lane = threadIdx.x & 63;
    const int wid  = threadIdx.x >> 6;
    const int gid  = blockIdx.x * 4 + wid;      // global query id, 0..8191
    const int b    = gid >> 10;                 // batch

    const float* batch_xyz = xyz + (size_t)b * NPTS * 3;
    const float* q = sxyz + (size_t)gid * 3;
    const float qx = q[0], qy = q[1], qz = q[2];

    // Wave-cooperative sorted top-K: lane j (j<10) holds j-th smallest (dist, idx)
    float kept_d = INFINITY;
    int   kept_i = 0;
    float thresh = INFINITY;   // current 10th-smallest, wave-uniform

    for (int tile = 0; tile < NPTS / TILE; ++tile) {
        __syncthreads();
        // cooperative tile load: 3072 floats = 768 float4, 256 threads
        const float4* src = (const float4*)(batch_xyz + (size_t)tile * TILE * 3);
        float4* dst = (float4*)tileS;
        #pragma unroll
        for (int t = 0; t < 3; ++t) dst[t * 256 + threadIdx.x] = src[t * 256 + threadIdx.x];
        __syncthreads();

        #pragma unroll 4
        for (int j = 0; j < TILE / 64; ++j) {
            const int p = j * 64 + lane;
            const float x = tileS[3 * p + 0];
            const float y = tileS[3 * p + 1];
            const float z = tileS[3 * p + 2];
            const float dx = x - qx, dy = y - qy, dz = z - qz;
            const float d = dx * dx + dy * dy + dz * dz;
            const int pidx = tile * TILE + p;

            unsigned long long mask = __ballot(d < thresh);
            while (mask) {
                const int w = __builtin_ctzll(mask);
                mask &= mask - 1;
                const float v  = __shfl(d, w);
                const int   vi = __shfl(pidx, w);
                if (v < thresh) {   // re-check vs updated threshold (uniform branch)
                    // insertion position = #kept entries strictly smaller
                    const unsigned long long sm = __ballot(kept_d < v);
                    const int pos = __popcll(sm);
                    const float ud = __shfl_up(kept_d, 1);
                    const int   ui = __shfl_up(kept_i, 1);
                    if (lane < KNN && lane >= pos) {
                        kept_d = (lane == pos) ? v  : ud;
                        kept_i = (lane == pos) ? vi : ui;
                    }
                    thresh = __shfl(kept_d, KNN - 1);
                }
            }
        }
    }

    // ---- epilogue: softmax over K neighbors + weighted coordinate sum ----
    const float t = temp[0];
    const float invt2 = 1.0f / (t * t);
    const float d0 = __shfl(kept_d, 0);   // smallest distance (softmax max-shift)

    float w = 0.f, px = 0.f, py = 0.f, pz = 0.f;
    if (lane < KNN) {
        w = __expf((d0 - kept_d) * invt2);
        const float* pp = batch_xyz + (size_t)kept_i * 3;
        px = pp[0]; py = pp[1]; pz = pp[2];
    }
    float sw = w, sx = w * px, sy = w * py, sz = w * pz;
    #pragma unroll
    for (int off = 8; off >= 1; off >>= 1) {
        sw += __shfl_xor(sw, off);
        sx += __shfl_xor(sx, off);
        sy += __shfl_xor(sy, off);
        sz += __shfl_xor(sz, off);
    }
    if (lane == 0) {
        const float inv = 1.0f / sw;
        out[(size_t)gid * 3 + 0] = sx * inv;
        out[(size_t)gid * 3 + 1] = sy * inv;
        out[(size_t)gid * 3 + 2] = sz * inv;
        if (gid == 0) out[NSMP_TOT * 3] = t;   // second tuple output: temp
    }
}

extern "C" void kernel_launch(void* const* d_in, const int* in_sizes, int n_in,
                              void* d_out, int out_size, void* d_ws, size_t ws_size,
                              hipStream_t stream) {
    const float* xyz  = (const float*)d_in[0];   // [8,16384,3]
    const float* sxyz = (const float*)d_in[1];   // [8,1024,3]
    const float* temp = (const float*)d_in[2];   // scalar
    float* out = (float*)d_out;                  // 8*1024*3 + 1 floats

    dim3 grid(NSMP_TOT / 4);   // 4 queries (waves) per block
    dim3 block(256);
    hipLaunchKernelGGL(softproj_kernel, grid, block, 0, stream, xyz, sxyz, temp, out);
}